// Round 4
// baseline (79363.586 us; speedup 1.0000x reference)
//
#include <hip/hip_runtime.h>
#include <math.h>

// B=128, T=256, H=E=1024, L=2, EOS=1
#define NB 128
#define NT 256
#define NH 1024
#define NE 1024
#define G4 4096
#define EOSL 1

// ---------------- workspace layout (float units) ----------------
// c    [(l*2+dir)][1024][128]            =   524,288
// Ht   [2dir][1024][128]                 =   262,144
// fcz  [16][128][1024]                   = 2,097,152
// bias [(l*2+dir)][4096]                 =    16,384
// ended 128, bar 64
// xph  2 parity bufs x 524,288 f (packed h frags, 2 MB each)
// xpx  packed x frags (0.5 MB)           =   131,072
// WP   packed weights [4ld][256mt][64kt][1024sh] = 33,554,432 f
#define C_OFF    ((size_t)0)
#define HT_OFF   ((size_t)524288)
#define FCZ_OFF  ((size_t)786432)
#define BIAS_OFF ((size_t)2883584)
#define END_OFF  ((size_t)2899968)
#define BAR_OFF  ((size_t)2900096)
#define XPH_OFF  ((size_t)2900160)
#define XPX_OFF  ((size_t)3948736)
#define WP_OFF   ((size_t)4079808)
#define TOTAL_MIN_F  ((size_t)4079808)
#define TOTAL_PACK_F ((size_t)37634240)   // ~150.5 MB

typedef __attribute__((ext_vector_type(8))) short s8v;   // 8 bf16 for MFMA A/B
typedef __attribute__((ext_vector_type(4))) float f4v;   // MFMA C/D

__device__ __forceinline__ float sigmoid_stable(float x) {
  if (x >= 0.f) return 1.f / (1.f + expf(-x));
  float ex = expf(x);
  return ex / (1.f + ex);
}
__device__ __forceinline__ unsigned short bf_rne(float x) {
  unsigned u = __float_as_uint(x);
  return (unsigned short)((u + 0x7FFFu + ((u >> 16) & 1u)) >> 16);
}
__device__ __forceinline__ void split_bf(float x, unsigned short& h, unsigned short& l) {
  unsigned u = __float_as_uint(x);
  unsigned hb = (u + 0x7FFFu + ((u >> 16) & 1u)) >> 16;
  h = (unsigned short)hb;
  float r = x - __uint_as_float(hb << 16);   // exact
  l = bf_rne(r);
}
__device__ __forceinline__ void cvt8(float4 a0, float4 a1, s8v& hi, s8v& lo)
{
  const float v[8] = {a0.x, a0.y, a0.z, a0.w, a1.x, a1.y, a1.z, a1.w};
  #pragma unroll
  for (int j = 0; j < 8; j++) {
    unsigned short h, l; split_bf(v[j], h, l);
    hi[j] = (short)h; lo[j] = (short)l;
  }
}

// frag layouts (verified rounds 0-3):
//  B (acts): lane l holds B[k=(l>>4)*8+r][b=l&15]; frag = 512 hi shorts + 512 lo shorts
//  A (wgts): lane l holds A[slot=l&15][k=(l>>4)*8+r]; same hi/lo structure.
//  NEW gate-interleaved mtile mapping: mtile = mb*2+half; slot s -> physical row
//  m = gate*1024 + mb*8 + (s&7), gate = half*2 + (s>>3).
//  C/D: col=lane&15 (b), row slot=(lane>>4)*4+reg.

// ---------------- grid barrier (device-scope, sense = generation counter) ----
__device__ __forceinline__ void gbar(int* cnt, int* gen, int& mygen)
{
  __syncthreads();
  if (threadIdx.x == 0) {
    __threadfence();                                   // release: wb L2
    int target = mygen + 1;
    if (__hip_atomic_fetch_add(cnt, 1, __ATOMIC_ACQ_REL, __HIP_MEMORY_SCOPE_AGENT)
        == (int)gridDim.x - 1) {
      __hip_atomic_store(cnt, 0, __ATOMIC_RELAXED, __HIP_MEMORY_SCOPE_AGENT);
      __hip_atomic_fetch_add(gen, 1, __ATOMIC_RELEASE, __HIP_MEMORY_SCOPE_AGENT);
    } else {
      int guard = 0;
      while (__hip_atomic_load(gen, __ATOMIC_ACQUIRE, __HIP_MEMORY_SCOPE_AGENT) < target) {
        __builtin_amdgcn_s_sleep(2);
        if (++guard > (1 << 20)) break;                // degrade, never hang
      }
    }
    mygen = target;
    __threadfence();                                   // acquire: inv L1/L2
  }
  __syncthreads();
}

// ---------------- init: pack h state (parity 0) + x0, c, fused bias, ended, bar --
__global__ void k_init(const int* yy, const float* h_t, const float* h_tr,
                       const float* c0, const float* c0r,
                       const float* b_ih, const float* b_hh,
                       const float* b_ihr, const float* b_hhr,
                       const float* emb,
                       unsigned short* xph, unsigned short* xpx,
                       float* call, float* bias, int* ended, int* bar)
{
  int idx = blockIdx.x * 256 + threadIdx.x;   // 2048 blocks -> 524288
  if (idx < 2 * 2048 * 128) {                 // XPH parity-0
    int dir = idx / (2048 * 128); int rem = idx % (2048 * 128);
    int row = rem >> 7, b = rem & 127;
    int l = row >> 10, n = row & 1023;
    const float* src = dir ? h_tr : h_t;
    float v = src[((size_t)l * 128 + b) * 1024 + n];
    unsigned short h, lo; split_bf(v, h, lo);
    size_t off = ((size_t)(dir * 64 + (row >> 5)) * 8 + (b >> 4)) * 1024
               + ((b & 15) + 16 * ((n >> 3) & 3)) * 8 + (n & 7);
    xph[off] = h; xph[off + 512] = lo;
  }
  if (idx < 4 * 1024 * 128) {                 // c[(l*2+dir)][n][b]
    int ld = idx / (1024 * 128); int l = ld >> 1, dir = ld & 1;
    int rem = idx % (1024 * 128); int n = rem >> 7;
    call[idx] = (dir ? c0r : c0)[l * 1024 + n];
  }
  if (idx < 4 * 4096) {                       // bias[(l*2+dir)][m]
    int ld = idx / 4096; int l = ld >> 1, dir = ld & 1;
    int m = idx & 4095;
    bias[idx] = (dir ? b_ihr : b_ih)[l * 4096 + m] + (dir ? b_hhr : b_hh)[l * 4096 + m];
  }
  if (idx < 128 * 1024) {                     // XPX: x0 = emb[yy[:,0]]
    int b = idx >> 10, k = idx & 1023;
    int e = yy[b * NT];
    float v = emb[(size_t)e * 1024 + k];
    unsigned short h, lo; split_bf(v, h, lo);
    size_t off = ((size_t)(k >> 5) * 8 + (b >> 4)) * 1024
               + ((b & 15) + 16 * ((k >> 3) & 3)) * 8 + (k & 7);
    xpx[off] = h; xpx[off + 512] = lo;
  }
  if (idx < NB) ended[idx] = 0;
  if (idx < 2) bar[idx] = 0;
}

// ---------------- one-time weight pre-split (gate-interleaved mtiles) --------
__global__ void k_packW(const float* W_ih, const float* W_hh,
                        const float* W_ihr, const float* W_hhr,
                        unsigned short* WP)
{
  int idx = blockIdx.x * 256 + threadIdx.x;   // 16384 blocks -> 4,194,304
  int l = idx & 63;
  int frag = idx >> 6;                        // ((ld*256+mtile)*64+ktile)
  int ktile = frag & 63;
  int mtile = (frag >> 6) & 255;
  int ld = frag >> 14;
  int layer = ld >> 1, dir = ld & 1;
  int s = l & 15;
  int mbb = mtile >> 1, half = mtile & 1;
  int gate = half * 2 + (s >> 3);
  int m = gate * 1024 + mbb * 8 + (s & 7);
  int kg = ktile * 32 + (l >> 4) * 8;
  const float* base;
  if (kg < 1024) base = (dir ? W_ihr : W_ih) + ((size_t)layer * 4096 + m) * 1024 + kg;
  else           base = (dir ? W_hhr : W_hh) + ((size_t)layer * 4096 + m) * 1024 + (kg - 1024);
  float4 a0 = *(const float4*)base, a1 = *(const float4*)(base + 4);
  s8v hi, lo; cvt8(a0, a1, hi, lo);
  unsigned short* outp = WP + (size_t)frag * 1024 + l * 8;
  *(s8v*)outp = hi;
  *(s8v*)(outp + 512) = lo;
}

// ---------------- reduction-tree helpers (verified round 3) ------------------
__device__ __forceinline__ void red_write(float* red, int slot, int l, const f4v (&acc)[2][8])
{
  #pragma unroll
  for (int mt = 0; mt < 2; mt++)
    #pragma unroll
    for (int bt = 0; bt < 8; bt++)
      *(f4v*)&red[(size_t)slot * 4096 + (mt * 8 + bt) * 256 + l * 4] = acc[mt][bt];
}
__device__ __forceinline__ void red_add(const float* red, int slot, int l, f4v (&acc)[2][8])
{
  #pragma unroll
  for (int mt = 0; mt < 2; mt++)
    #pragma unroll
    for (int bt = 0; bt < 8; bt++)
      acc[mt][bt] += *(const f4v*)&red[(size_t)slot * 4096 + (mt * 8 + bt) * 256 + l * 4];
}

struct KP {
  const unsigned short* WP;
  const float* Wih; const float* Whh; const float* Wihr; const float* Whhr;
  const float* bias; float* c; float* Ht; float* fcz;
  unsigned short* xph; unsigned short* xpx;
  const float* fcW; const float* fcb; const float* emb;
  float* out; int* ended; int* bar;
};

// ---------------- persistent kernel: all 256 steps, 4 grid barriers/step -----
template<int PACKED>
__global__ __launch_bounds__(512, 2) void k_all(KP p)
{
  __shared__ __align__(16) float lds[16384];           // 64 KB, reused per phase
  const int bid = blockIdx.x, tid = threadIdx.x;
  const int l = tid & 63, w = tid >> 6;                // w = K-chunk 0..7 (gemm)
  const int dir = bid >> 7, mb = bid & 127;
  const int lr = l & 15, lk = l >> 4;
  int mygen = 0;

  for (int t = 0; t < NT; t++) {
    unsigned short* xpR = p.xph + (size_t)(t & 1) * 1048576;        // read h
    unsigned short* xpW = p.xph + (size_t)((t & 1) ^ 1) * 1048576;  // write h

    for (int layer = 0; layer < 2; layer++) {
      // ---- per-wave B fragment base ----
      const unsigned short* Bb;
      if (layer == 0)
        Bb = (w < 4) ? p.xpx + (size_t)w * 65536
                     : xpR + (size_t)(dir * 64 + (w - 4) * 8) * 8192;
      else
        Bb = (w < 4) ? xpW + (size_t)(dir * 64 + w * 8) * 8192
                     : xpR + (size_t)(dir * 64 + 32 + (w - 4) * 8) * 8192;
      Bb += l * 8;

      f4v acc[2][8];
      #pragma unroll
      for (int mt = 0; mt < 2; mt++)
        #pragma unroll
        for (int bt = 0; bt < 8; bt++)
          acc[mt][bt] = (f4v)(0.0f);

      if (PACKED) {
        const unsigned short* Wb = p.WP + (size_t)(layer * 2 + dir) * 16777216ULL
            + (((size_t)(mb * 2) * 64 + (size_t)w * 8) << 10) + l * 8;
        s8v whc[2], wlc[2];
        #pragma unroll
        for (int mt = 0; mt < 2; mt++) {
          const unsigned short* q = Wb + ((size_t)(mt * 64) << 10);
          whc[mt] = *(const s8v*)q; wlc[mt] = *(const s8v*)(q + 512);
        }
        #pragma unroll 1
        for (int kk = 0; kk < 8; kk++) {
          s8v bh[8], bl[8];
          #pragma unroll
          for (int bt = 0; bt < 8; bt++) {
            const unsigned short* q = Bb + ((size_t)(kk * 8 + bt) << 10);
            bh[bt] = *(const s8v*)q; bl[bt] = *(const s8v*)(q + 512);
          }
          s8v whn[2], wln[2];
          if (kk < 7) {
            #pragma unroll
            for (int mt = 0; mt < 2; mt++) {
              const unsigned short* q = Wb + ((size_t)(mt * 64 + kk + 1) << 10);
              whn[mt] = *(const s8v*)q; wln[mt] = *(const s8v*)(q + 512);
            }
          }
          #pragma unroll
          for (int mt = 0; mt < 2; mt++)
            #pragma unroll
            for (int bt = 0; bt < 8; bt++) {
              acc[mt][bt] = __builtin_amdgcn_mfma_f32_16x16x32_bf16(whc[mt], bh[bt], acc[mt][bt], 0, 0, 0);
              acc[mt][bt] = __builtin_amdgcn_mfma_f32_16x16x32_bf16(whc[mt], bl[bt], acc[mt][bt], 0, 0, 0);
              acc[mt][bt] = __builtin_amdgcn_mfma_f32_16x16x32_bf16(wlc[mt], bh[bt], acc[mt][bt], 0, 0, 0);
            }
          if (kk < 7) {
            whc[0] = whn[0]; whc[1] = whn[1];
            wlc[0] = wln[0]; wlc[1] = wln[1];
          }
        }
      } else {
        const float* Wsel = ((w < 4) ? (dir ? p.Wihr : p.Wih) : (dir ? p.Whhr : p.Whh))
                          + (size_t)layer * 4194304;
        int col0 = (w & 3) * 256 + lk * 8;
        const float* Wrow[2];
        Wrow[0] = Wsel + ((size_t)(((lr >> 3)) * 1024 + mb * 8 + (lr & 7))) * 1024 + col0;
        Wrow[1] = Wsel + ((size_t)((2 + (lr >> 3)) * 1024 + mb * 8 + (lr & 7))) * 1024 + col0;
        float4 ac[2][2];
        #pragma unroll
        for (int mt = 0; mt < 2; mt++) {
          ac[mt][0] = *(const float4*)(Wrow[mt]);
          ac[mt][1] = *(const float4*)(Wrow[mt] + 4);
        }
        #pragma unroll 1
        for (int kk = 0; kk < 8; kk++) {
          s8v bh[8], bl[8];
          #pragma unroll
          for (int bt = 0; bt < 8; bt++) {
            const unsigned short* q = Bb + ((size_t)(kk * 8 + bt) << 10);
            bh[bt] = *(const s8v*)q; bl[bt] = *(const s8v*)(q + 512);
          }
          float4 an[2][2];
          if (kk < 7) {
            #pragma unroll
            for (int mt = 0; mt < 2; mt++) {
              an[mt][0] = *(const float4*)(Wrow[mt] + (kk + 1) * 32);
              an[mt][1] = *(const float4*)(Wrow[mt] + (kk + 1) * 32 + 4);
            }
          }
          #pragma unroll
          for (int mt = 0; mt < 2; mt++) {
            s8v wh, wl;
            cvt8(ac[mt][0], ac[mt][1], wh, wl);
            #pragma unroll
            for (int bt = 0; bt < 8; bt++) {
              acc[mt][bt] = __builtin_amdgcn_mfma_f32_16x16x32_bf16(wh, bh[bt], acc[mt][bt], 0, 0, 0);
              acc[mt][bt] = __builtin_amdgcn_mfma_f32_16x16x32_bf16(wh, bl[bt], acc[mt][bt], 0, 0, 0);
              acc[mt][bt] = __builtin_amdgcn_mfma_f32_16x16x32_bf16(wl, bh[bt], acc[mt][bt], 0, 0, 0);
            }
          }
          if (kk < 7) {
            #pragma unroll
            for (int mt = 0; mt < 2; mt++) { ac[mt][0] = an[mt][0]; ac[mt][1] = an[mt][1]; }
          }
        }
      }

      // ---- in-block K reduction: 8 -> 4 -> 2 -> zs stage ----
      if (w >= 4) red_write(lds, w - 4, l, acc);
      __syncthreads();
      if (w < 4) red_add(lds, w, l, acc);
      __syncthreads();
      if (w == 2 || w == 3) red_write(lds, w - 2, l, acc);
      __syncthreads();
      if (w < 2) red_add(lds, w, l, acc);
      __syncthreads();
      if (w < 2) red_write(lds, w, l, acc);
      __syncthreads();
      float* zs = lds + 8192;                 // [2mt][16slot][128b], slot-2 region
      #pragma unroll
      for (int vi = 0; vi < 2; vi++) {
        int v = tid + vi * 512;
        f4v s = *(const f4v*)&lds[(size_t)v * 4];
        s += *(const f4v*)&lds[4096 + (size_t)v * 4];
        int frag = v >> 6, lane = v & 63;
        int mt = frag >> 3, bt = frag & 7;
        int s0 = (lane >> 4) * 4, bcol = bt * 16 + (lane & 15);
        #pragma unroll
        for (int r = 0; r < 4; r++)
          zs[mt * 2048 + (s0 + r) * 128 + bcol] = s[r];
      }
      __syncthreads();

      // ---- fused gates: slots {0-7,8-15} of mt0 = i,f ; mt1 = g,o ----
      int ld = layer * 2 + dir;
      #pragma unroll
      for (int half = 0; half < 2; half++) {
        int cell = tid + half * 512;
        int nl = cell >> 7, b = cell & 127;
        int n = mb * 8 + nl;
        float iv = zs[nl * 128 + b]              + p.bias[ld * 4096 + n];
        float fv = zs[(nl + 8) * 128 + b]        + p.bias[ld * 4096 + 1024 + n];
        float gv = zs[2048 + nl * 128 + b]       + p.bias[ld * 4096 + 2048 + n];
        float ov = zs[2048 + (nl + 8) * 128 + b] + p.bias[ld * 4096 + 3072 + n];
        float* cp = p.c + ((size_t)ld * 1024 + n) * 128 + b;
        float cold = *cp;
        float cn = sigmoid_stable(fv) * cold + sigmoid_stable(iv) * tanhf(gv);
        float hn = sigmoid_stable(ov) * tanhf(cn);
        *cp = cn;
        int kt = layer * 32 + (n >> 5), n5 = n & 31;
        size_t off = ((size_t)(dir * 64 + kt) * 8 + (b >> 4)) * 1024
                   + ((b & 15) + 16 * ((n5 >> 3) & 3)) * 8 + (n5 & 7);
        unsigned short hh, lo; split_bf(hn, hh, lo);
        xpW[off] = hh; xpW[off + 512] = lo;
        if (layer == 1)
          p.Ht[(size_t)dir * 131072 + (size_t)n * 128 + b] = hn;
      }
      gbar(p.bar, p.bar + 1, mygen);
    } // layer

    // ---- fc: fcz[kp][b][e] partials, 256 blocks = (16 et, 16 kp) ----
    {
      int et = bid & 15, kp = bid >> 4;
      int e0 = et * 64, k00 = kp * 128;
      float* in_s = lds;            // [128][36]
      float* w_s  = lds + 4608;     // [64][36]
      int e_sub = tid & 7, bg = tid >> 3, b0 = bg * 2;
      float accf[8][2];
      #pragma unroll
      for (int je = 0; je < 8; je++) { accf[je][0] = 0.f; accf[je][1] = 0.f; }
      for (int kc = 0; kc < 128; kc += 32) {
        #pragma unroll
        for (int i = 0; i < 2; i++) {
          int flat = tid + 512 * i, r = flat >> 3, f4i = flat & 7;
          float4 v = *(const float4*)(p.Ht + (size_t)r * 2048 + k00 + kc + f4i * 4);
          int sw = (f4i ^ (r >> 2)) & 7;
          *(float4*)&in_s[r * 36 + sw * 4] = v;
        }
        {
          int r = tid >> 3, f4i = tid & 7;
          *(float4*)&w_s[r * 36 + f4i * 4] =
              *(const float4*)(p.fcW + (size_t)(e0 + r) * 2048 + k00 + kc + f4i * 4);
        }
        __syncthreads();
        #pragma unroll
        for (int kq = 0; kq < 8; kq++) {
          int ksw = (kq ^ (bg >> 1)) & 7;
          float4 a0 = *(const float4*)&in_s[b0 * 36 + ksw * 4];
          float4 a1 = *(const float4*)&in_s[(b0 + 1) * 36 + ksw * 4];
          #pragma unroll
          for (int je = 0; je < 8; je++) {
            float4 w4 = *(const float4*)&w_s[(e_sub + 8 * je) * 36 + kq * 4];
            accf[je][0] += a0.x * w4.x + a0.y * w4.y + a0.z * w4.z + a0.w * w4.w;
            accf[je][1] += a1.x * w4.x + a1.y * w4.y + a1.z * w4.z + a1.w * w4.w;
          }
        }
        __syncthreads();
      }
      #pragma unroll
      for (int je = 0; je < 8; je++) {
        int e = e0 + e_sub + 8 * je;
        p.fcz[((size_t)kp * 128 + b0) * 1024 + e]     = accf[je][0];
        p.fcz[((size_t)kp * 128 + b0 + 1) * 1024 + e] = accf[je][1];
      }
      gbar(p.bar, p.bar + 1, mygen);
    }

    // ---- final: logits, argmax, softmax, pack next x (blocks 0..127) ----
    if (bid < 128) {
      int b = bid;
      float* sval = lds;
      int*   sidx = (int*)(lds + 512);
      float* ssum = lds + 1024;
      bool end = (p.ended[b] != 0);
      int e2 = tid * 2;
      float vx = p.fcb[e2], vy = p.fcb[e2 + 1];
      #pragma unroll
      for (int q = 0; q < 16; q++) {
        const float* f = &p.fcz[((size_t)q * 128 + b) * 1024 + e2];
        vx += f[0]; vy += f[1];
      }
      if (end) { vx = (e2 == EOSL) ? 1.f : 0.f; vy = (e2 + 1 == EOSL) ? 1.f : 0.f; }
      float bv; int bi;
      if (vy > vx) { bv = vy; bi = e2 + 1; } else { bv = vx; bi = e2; }
      sval[tid] = bv; sidx[tid] = bi;
      __syncthreads();
      for (int s = 256; s > 0; s >>= 1) {
        if (tid < s) {
          float ov = sval[tid + s]; int oi = sidx[tid + s];
          if (ov > sval[tid] || (ov == sval[tid] && oi < sidx[tid])) { sval[tid] = ov; sidx[tid] = oi; }
        }
        __syncthreads();
      }
      float m = sval[0]; int label = sidx[0];
      {
        int k0 = tid * 2;
        float ex = p.emb[(size_t)label * 1024 + k0];
        float ey = p.emb[(size_t)label * 1024 + k0 + 1];
        size_t off = ((size_t)(k0 >> 5) * 8 + (b >> 4)) * 1024
                   + ((b & 15) + 16 * ((k0 >> 3) & 3)) * 8 + (k0 & 7);
        unsigned short h0, l0, h1, l1;
        split_bf(ex, h0, l0); split_bf(ey, h1, l1);
        p.xpx[off] = h0; p.xpx[off + 1] = h1;
        p.xpx[off + 512] = l0; p.xpx[off + 513] = l1;
      }
      float ex0 = expf(vx - m), ex1 = expf(vy - m);
      ssum[tid] = ex0 + ex1;
      __syncthreads();
      for (int s = 256; s > 0; s >>= 1) { if (tid < s) ssum[tid] += ssum[tid + s]; __syncthreads(); }
      float inv = 1.f / ssum[0];
      float* orow = p.out + ((size_t)b * NT + t) * NE + e2;
      orow[0] = ex0 * inv; orow[1] = ex1 * inv;
      if (tid == 0) p.ended[b] = (end || label == EOSL) ? 1 : 0;
    }
    gbar(p.bar, p.bar + 1, mygen);
  } // t
}

extern "C" void kernel_launch(void* const* d_in, const int* in_sizes, int n_in,
                              void* d_out, int out_size, void* d_ws, size_t ws_size,
                              hipStream_t stream)
{
  const int*   yy    = (const int*)d_in[0];
  const float* h_t   = (const float*)d_in[1];
  const float* h_tr  = (const float*)d_in[2];
  const float* emb   = (const float*)d_in[4];
  const float* W_ih  = (const float*)d_in[5];
  const float* W_hh  = (const float*)d_in[6];
  const float* b_ih  = (const float*)d_in[7];
  const float* b_hh  = (const float*)d_in[8];
  const float* W_ihr = (const float*)d_in[9];
  const float* W_hhr = (const float*)d_in[10];
  const float* b_ihr = (const float*)d_in[11];
  const float* b_hhr = (const float*)d_in[12];
  const float* c0    = (const float*)d_in[13];
  const float* c0r   = (const float*)d_in[14];
  const float* fc_W  = (const float*)d_in[15];
  const float* fc_b  = (const float*)d_in[16];
  float* out = (float*)d_out;

  float* ws = (float*)d_ws;
  KP p;
  p.c     = ws + C_OFF;
  p.Ht    = ws + HT_OFF;
  p.fcz   = ws + FCZ_OFF;
  p.bias  = ws + BIAS_OFF;
  p.ended = (int*)(ws + END_OFF);
  p.bar   = (int*)(ws + BAR_OFF);
  p.xph   = (unsigned short*)(ws + XPH_OFF);
  p.xpx   = (unsigned short*)(ws + XPX_OFF);
  p.WP    = (const unsigned short*)(ws + WP_OFF);
  p.Wih = W_ih; p.Whh = W_hh; p.Wihr = W_ihr; p.Whhr = W_hhr;
  p.fcW = fc_W; p.fcb = fc_b; p.emb = emb;
  p.out = out;
  bool packed = ws_size >= TOTAL_PACK_F * sizeof(float);

  k_init<<<2048, 256, 0, stream>>>(yy, h_t, h_tr, c0, c0r, b_ih, b_hh, b_ihr, b_hhr,
                                   emb, p.xph, p.xpx, p.c, (float*)p.bias,
                                   p.ended, p.bar);
  if (packed)
    k_packW<<<16384, 256, 0, stream>>>(W_ih, W_hh, W_ihr, W_hhr,
                                       (unsigned short*)p.WP);

  if (packed) k_all<1><<<256, 512, 0, stream>>>(p);
  else        k_all<0><<<256, 512, 0, stream>>>(p);
}

// Round 5
// 66749.054 us; speedup vs baseline: 1.1890x; 1.1890x over previous
//
#include <hip/hip_runtime.h>
#include <math.h>

// B=128, T=256, H=E=1024, L=2, EOS=1
#define NB 128
#define NT 256
#define NH 1024
#define NE 1024
#define G4 4096
#define EOSL 1

// ---------------- workspace layout (float units) ----------------
#define C_OFF    ((size_t)0)
#define HT_OFF   ((size_t)524288)
#define FCZ_OFF  ((size_t)786432)
#define BIAS_OFF ((size_t)2883584)
#define END_OFF  ((size_t)2899968)
#define BAR_OFF  ((size_t)2900096)
#define XPH_OFF  ((size_t)2900160)
#define XPX_OFF  ((size_t)3948736)
#define WP_OFF   ((size_t)4079808)
#define TOTAL_MIN_F  ((size_t)4079808)
#define TOTAL_PACK_F ((size_t)37634240)   // ~150.5 MB

typedef __attribute__((ext_vector_type(8))) short s8v;   // 8 bf16 for MFMA A/B
typedef __attribute__((ext_vector_type(4))) float f4v;   // MFMA C/D

__device__ __forceinline__ float sigmoid_stable(float x) {
  if (x >= 0.f) return 1.f / (1.f + expf(-x));
  float ex = expf(x);
  return ex / (1.f + ex);
}
__device__ __forceinline__ unsigned short bf_rne(float x) {
  unsigned u = __float_as_uint(x);
  return (unsigned short)((u + 0x7FFFu + ((u >> 16) & 1u)) >> 16);
}
__device__ __forceinline__ void split_bf(float x, unsigned short& h, unsigned short& l) {
  unsigned u = __float_as_uint(x);
  unsigned hb = (u + 0x7FFFu + ((u >> 16) & 1u)) >> 16;
  h = (unsigned short)hb;
  float r = x - __uint_as_float(hb << 16);   // exact
  l = bf_rne(r);
}
__device__ __forceinline__ void cvt8(float4 a0, float4 a1, s8v& hi, s8v& lo)
{
  const float v[8] = {a0.x, a0.y, a0.z, a0.w, a1.x, a1.y, a1.z, a1.w};
  #pragma unroll
  for (int j = 0; j < 8; j++) {
    unsigned short h, l; split_bf(v[j], h, l);
    hi[j] = (short)h; lo[j] = (short)l;
  }
}

// ---- coherent write-through stores (bypass/through L2 -> L3 coherence point).
// No dirty L2 lines are ever created by k_all, so buffer_inv is always safe.
__device__ __forceinline__ void st_f(float* p, float v) {
  asm volatile("global_store_dword %0, %1, off sc0 sc1" :: "v"(p), "v"(v) : "memory");
}
__device__ __forceinline__ void st_u32(unsigned* p, unsigned v) {
  asm volatile("global_store_dword %0, %1, off sc0 sc1" :: "v"(p), "v"(v) : "memory");
}
__device__ __forceinline__ void st_h(unsigned short* p, unsigned short v) {
  unsigned vv = v;
  asm volatile("global_store_short %0, %1, off sc0 sc1" :: "v"(p), "v"(vv) : "memory");
}
__device__ __forceinline__ void st_f2(float* p, float a, float b) {
  float2 v; v.x = a; v.y = b;
  asm volatile("global_store_dwordx2 %0, %1, off sc0 sc1" :: "v"(p), "v"(v) : "memory");
}

// frag layouts (verified rounds 0-4):
//  B (acts): lane l holds B[k=(l>>4)*8+r][b=l&15]; frag = 512 hi shorts + 512 lo shorts
//  A (wgts): lane l holds A[slot=l&15][k=(l>>4)*8+r]; same hi/lo structure.
//  gate-interleaved mtile mapping: mtile = mb*2+half; slot s -> physical row
//  m = gate*1024 + mb*8 + (s&7), gate = half*2 + (s>>3).
//  C/D: col=lane&15 (b), row slot=(lane>>4)*4+reg.

// ---------------- grid barrier: monotonic counter, relaxed spin, inv-only ----
__device__ __forceinline__ void gbar(int* cnt, int& nbar)
{
  // drain this wave's write-through stores to the coherence point
  asm volatile("s_waitcnt vmcnt(0)" ::: "memory");
  __syncthreads();                       // all waves' stores drained
  if (threadIdx.x == 0) {
    int target = (++nbar) * (int)gridDim.x;
    __hip_atomic_fetch_add(cnt, 1, __ATOMIC_RELEASE, __HIP_MEMORY_SCOPE_AGENT);
    int guard = 0;
    while (__hip_atomic_load(cnt, __ATOMIC_RELAXED, __HIP_MEMORY_SCOPE_AGENT) < target) {
      __builtin_amdgcn_s_sleep(4);
      if (++guard > (1 << 14)) break;    // degrade, never hang
    }
  }
  __syncthreads();
  // invalidate clean L1/L2 so post-barrier loads see L3-coherent data
  asm volatile("buffer_inv sc1" ::: "memory");
}

// ---------------- init: pack h state (parity 0) + x0, c, fused bias, ended, bar --
__global__ void k_init(const int* yy, const float* h_t, const float* h_tr,
                       const float* c0, const float* c0r,
                       const float* b_ih, const float* b_hh,
                       const float* b_ihr, const float* b_hhr,
                       const float* emb,
                       unsigned short* xph, unsigned short* xpx,
                       float* call, float* bias, int* ended, int* bar)
{
  int idx = blockIdx.x * 256 + threadIdx.x;   // 2048 blocks -> 524288
  if (idx < 2 * 2048 * 128) {                 // XPH parity-0
    int dir = idx / (2048 * 128); int rem = idx % (2048 * 128);
    int row = rem >> 7, b = rem & 127;
    int l = row >> 10, n = row & 1023;
    const float* src = dir ? h_tr : h_t;
    float v = src[((size_t)l * 128 + b) * 1024 + n];
    unsigned short h, lo; split_bf(v, h, lo);
    size_t off = ((size_t)(dir * 64 + (row >> 5)) * 8 + (b >> 4)) * 1024
               + ((b & 15) + 16 * ((n >> 3) & 3)) * 8 + (n & 7);
    xph[off] = h; xph[off + 512] = lo;
  }
  if (idx < 4 * 1024 * 128) {                 // c[(l*2+dir)][n][b]
    int ld = idx / (1024 * 128); int l = ld >> 1, dir = ld & 1;
    int rem = idx % (1024 * 128); int n = rem >> 7;
    call[idx] = (dir ? c0r : c0)[l * 1024 + n];
  }
  if (idx < 4 * 4096) {                       // bias[(l*2+dir)][m]
    int ld = idx / 4096; int l = ld >> 1, dir = ld & 1;
    int m = idx & 4095;
    bias[idx] = (dir ? b_ihr : b_ih)[l * 4096 + m] + (dir ? b_hhr : b_hh)[l * 4096 + m];
  }
  if (idx < 128 * 1024) {                     // XPX: x0 = emb[yy[:,0]]
    int b = idx >> 10, k = idx & 1023;
    int e = yy[b * NT];
    float v = emb[(size_t)e * 1024 + k];
    unsigned short h, lo; split_bf(v, h, lo);
    size_t off = ((size_t)(k >> 5) * 8 + (b >> 4)) * 1024
               + ((b & 15) + 16 * ((k >> 3) & 3)) * 8 + (k & 7);
    xpx[off] = h; xpx[off + 512] = lo;
  }
  if (idx < NB) ended[idx] = 0;
  if (idx < 16) bar[idx] = 0;
}

// ---------------- one-time weight pre-split (gate-interleaved mtiles) --------
__global__ void k_packW(const float* W_ih, const float* W_hh,
                        const float* W_ihr, const float* W_hhr,
                        unsigned short* WP)
{
  int idx = blockIdx.x * 256 + threadIdx.x;   // 16384 blocks -> 4,194,304
  int l = idx & 63;
  int frag = idx >> 6;                        // ((ld*256+mtile)*64+ktile)
  int ktile = frag & 63;
  int mtile = (frag >> 6) & 255;
  int ld = frag >> 14;
  int layer = ld >> 1, dir = ld & 1;
  int s = l & 15;
  int mbb = mtile >> 1, half = mtile & 1;
  int gate = half * 2 + (s >> 3);
  int m = gate * 1024 + mbb * 8 + (s & 7);
  int kg = ktile * 32 + (l >> 4) * 8;
  const float* base;
  if (kg < 1024) base = (dir ? W_ihr : W_ih) + ((size_t)layer * 4096 + m) * 1024 + kg;
  else           base = (dir ? W_hhr : W_hh) + ((size_t)layer * 4096 + m) * 1024 + (kg - 1024);
  float4 a0 = *(const float4*)base, a1 = *(const float4*)(base + 4);
  s8v hi, lo; cvt8(a0, a1, hi, lo);
  unsigned short* outp = WP + (size_t)frag * 1024 + l * 8;
  *(s8v*)outp = hi;
  *(s8v*)(outp + 512) = lo;
}

// ---------------- reduction-tree helpers (verified round 3) ------------------
__device__ __forceinline__ void red_write(float* red, int slot, int l, const f4v (&acc)[2][8])
{
  #pragma unroll
  for (int mt = 0; mt < 2; mt++)
    #pragma unroll
    for (int bt = 0; bt < 8; bt++)
      *(f4v*)&red[(size_t)slot * 4096 + (mt * 8 + bt) * 256 + l * 4] = acc[mt][bt];
}
__device__ __forceinline__ void red_add(const float* red, int slot, int l, f4v (&acc)[2][8])
{
  #pragma unroll
  for (int mt = 0; mt < 2; mt++)
    #pragma unroll
    for (int bt = 0; bt < 8; bt++)
      acc[mt][bt] += *(const f4v*)&red[(size_t)slot * 4096 + (mt * 8 + bt) * 256 + l * 4];
}

struct KP {
  const unsigned short* WP;
  const float* Wih; const float* Whh; const float* Wihr; const float* Whhr;
  const float* bias; float* c; float* Ht; float* fcz;
  unsigned short* xph; unsigned short* xpx;
  const float* fcW; const float* fcb; const float* emb;
  float* out; int* ended; int* bar;
};

// ---------------- persistent kernel: all 256 steps, 4 grid barriers/step -----
template<int PACKED>
__global__ __launch_bounds__(512, 2) void k_all(KP p)
{
  __shared__ __align__(16) float lds[16384];           // 64 KB, reused per phase
  const int bid = blockIdx.x, tid = threadIdx.x;
  const int l = tid & 63, w = tid >> 6;                // w = K-chunk 0..7 (gemm)
  const int dir = bid >> 7, mb = bid & 127;
  const int lr = l & 15, lk = l >> 4;
  int nbar = 0;

  for (int t = 0; t < NT; t++) {
    unsigned short* xpR = p.xph + (size_t)(t & 1) * 1048576;        // read h
    unsigned short* xpW = p.xph + (size_t)((t & 1) ^ 1) * 1048576;  // write h

    for (int layer = 0; layer < 2; layer++) {
      // ---- per-wave B fragment base ----
      const unsigned short* Bb;
      if (layer == 0)
        Bb = (w < 4) ? p.xpx + (size_t)w * 65536
                     : xpR + (size_t)(dir * 64 + (w - 4) * 8) * 8192;
      else
        Bb = (w < 4) ? xpW + (size_t)(dir * 64 + w * 8) * 8192
                     : xpR + (size_t)(dir * 64 + 32 + (w - 4) * 8) * 8192;
      Bb += l * 8;

      f4v acc[2][8];
      #pragma unroll
      for (int mt = 0; mt < 2; mt++)
        #pragma unroll
        for (int bt = 0; bt < 8; bt++)
          acc[mt][bt] = (f4v)(0.0f);

      if (PACKED) {
        const unsigned short* Wb = p.WP + (size_t)(layer * 2 + dir) * 16777216ULL
            + (((size_t)(mb * 2) * 64 + (size_t)w * 8) << 10) + l * 8;
        s8v whc[2], wlc[2];
        #pragma unroll
        for (int mt = 0; mt < 2; mt++) {
          const unsigned short* q = Wb + ((size_t)(mt * 64) << 10);
          whc[mt] = *(const s8v*)q; wlc[mt] = *(const s8v*)(q + 512);
        }
        #pragma unroll 1
        for (int kk = 0; kk < 8; kk++) {
          s8v bh[8], bl[8];
          #pragma unroll
          for (int bt = 0; bt < 8; bt++) {
            const unsigned short* q = Bb + ((size_t)(kk * 8 + bt) << 10);
            bh[bt] = *(const s8v*)q; bl[bt] = *(const s8v*)(q + 512);
          }
          s8v whn[2], wln[2];
          if (kk < 7) {
            #pragma unroll
            for (int mt = 0; mt < 2; mt++) {
              const unsigned short* q = Wb + ((size_t)(mt * 64 + kk + 1) << 10);
              whn[mt] = *(const s8v*)q; wln[mt] = *(const s8v*)(q + 512);
            }
          }
          #pragma unroll
          for (int mt = 0; mt < 2; mt++)
            #pragma unroll
            for (int bt = 0; bt < 8; bt++) {
              acc[mt][bt] = __builtin_amdgcn_mfma_f32_16x16x32_bf16(whc[mt], bh[bt], acc[mt][bt], 0, 0, 0);
              acc[mt][bt] = __builtin_amdgcn_mfma_f32_16x16x32_bf16(whc[mt], bl[bt], acc[mt][bt], 0, 0, 0);
              acc[mt][bt] = __builtin_amdgcn_mfma_f32_16x16x32_bf16(wlc[mt], bh[bt], acc[mt][bt], 0, 0, 0);
            }
          if (kk < 7) {
            whc[0] = whn[0]; whc[1] = whn[1];
            wlc[0] = wln[0]; wlc[1] = wln[1];
          }
        }
      } else {
        const float* Wsel = ((w < 4) ? (dir ? p.Wihr : p.Wih) : (dir ? p.Whhr : p.Whh))
                          + (size_t)layer * 4194304;
        int col0 = (w & 3) * 256 + lk * 8;
        const float* Wrow[2];
        Wrow[0] = Wsel + ((size_t)(((lr >> 3)) * 1024 + mb * 8 + (lr & 7))) * 1024 + col0;
        Wrow[1] = Wsel + ((size_t)((2 + (lr >> 3)) * 1024 + mb * 8 + (lr & 7))) * 1024 + col0;
        float4 ac[2][2];
        #pragma unroll
        for (int mt = 0; mt < 2; mt++) {
          ac[mt][0] = *(const float4*)(Wrow[mt]);
          ac[mt][1] = *(const float4*)(Wrow[mt] + 4);
        }
        #pragma unroll 1
        for (int kk = 0; kk < 8; kk++) {
          s8v bh[8], bl[8];
          #pragma unroll
          for (int bt = 0; bt < 8; bt++) {
            const unsigned short* q = Bb + ((size_t)(kk * 8 + bt) << 10);
            bh[bt] = *(const s8v*)q; bl[bt] = *(const s8v*)(q + 512);
          }
          float4 an[2][2];
          if (kk < 7) {
            #pragma unroll
            for (int mt = 0; mt < 2; mt++) {
              an[mt][0] = *(const float4*)(Wrow[mt] + (kk + 1) * 32);
              an[mt][1] = *(const float4*)(Wrow[mt] + (kk + 1) * 32 + 4);
            }
          }
          #pragma unroll
          for (int mt = 0; mt < 2; mt++) {
            s8v wh, wl;
            cvt8(ac[mt][0], ac[mt][1], wh, wl);
            #pragma unroll
            for (int bt = 0; bt < 8; bt++) {
              acc[mt][bt] = __builtin_amdgcn_mfma_f32_16x16x32_bf16(wh, bh[bt], acc[mt][bt], 0, 0, 0);
              acc[mt][bt] = __builtin_amdgcn_mfma_f32_16x16x32_bf16(wh, bl[bt], acc[mt][bt], 0, 0, 0);
              acc[mt][bt] = __builtin_amdgcn_mfma_f32_16x16x32_bf16(wl, bh[bt], acc[mt][bt], 0, 0, 0);
            }
          }
          if (kk < 7) {
            #pragma unroll
            for (int mt = 0; mt < 2; mt++) { ac[mt][0] = an[mt][0]; ac[mt][1] = an[mt][1]; }
          }
        }
      }

      // ---- in-block K reduction: 8 -> 4 -> 2 -> zs stage ----
      if (w >= 4) red_write(lds, w - 4, l, acc);
      __syncthreads();
      if (w < 4) red_add(lds, w, l, acc);
      __syncthreads();
      if (w == 2 || w == 3) red_write(lds, w - 2, l, acc);
      __syncthreads();
      if (w < 2) red_add(lds, w, l, acc);
      __syncthreads();
      if (w < 2) red_write(lds, w, l, acc);
      __syncthreads();
      float* zs = lds + 8192;                 // [2mt][16slot][128b]
      #pragma unroll
      for (int vi = 0; vi < 2; vi++) {
        int v = tid + vi * 512;
        f4v s = *(const f4v*)&lds[(size_t)v * 4];
        s += *(const f4v*)&lds[4096 + (size_t)v * 4];
        int frag = v >> 6, lane = v & 63;
        int mt = frag >> 3, bt = frag & 7;
        int s0 = (lane >> 4) * 4, bcol = bt * 16 + (lane & 15);
        #pragma unroll
        for (int r = 0; r < 4; r++)
          zs[mt * 2048 + (s0 + r) * 128 + bcol] = s[r];
      }
      __syncthreads();

      // ---- fused gates: slots {0-7,8-15} of mt0 = i,f ; mt1 = g,o ----
      int ld = layer * 2 + dir;
      #pragma unroll
      for (int half = 0; half < 2; half++) {
        int cell = tid + half * 512;
        int nl = cell >> 7, b = cell & 127;
        int n = mb * 8 + nl;
        float iv = zs[nl * 128 + b]              + p.bias[ld * 4096 + n];
        float fv = zs[(nl + 8) * 128 + b]        + p.bias[ld * 4096 + 1024 + n];
        float gv = zs[2048 + nl * 128 + b]       + p.bias[ld * 4096 + 2048 + n];
        float ov = zs[2048 + (nl + 8) * 128 + b] + p.bias[ld * 4096 + 3072 + n];
        float* cp = p.c + ((size_t)ld * 1024 + n) * 128 + b;
        float cold = *cp;
        float cn = sigmoid_stable(fv) * cold + sigmoid_stable(iv) * tanhf(gv);
        float hn = sigmoid_stable(ov) * tanhf(cn);
        st_f(cp, cn);
        int kt = layer * 32 + (n >> 5), n5 = n & 31;
        size_t off = ((size_t)(dir * 64 + kt) * 8 + (b >> 4)) * 1024
                   + ((b & 15) + 16 * ((n5 >> 3) & 3)) * 8 + (n5 & 7);
        unsigned short hh, lo; split_bf(hn, hh, lo);
        st_h(xpW + off, hh);
        st_h(xpW + off + 512, lo);
        if (layer == 1)
          st_f(p.Ht + (size_t)dir * 131072 + (size_t)n * 128 + b, hn);
      }
      gbar(p.bar, nbar);
    } // layer

    // ---- fc: fcz[kp][b][e] partials, 256 blocks = (16 et, 16 kp) ----
    {
      int et = bid & 15, kp = bid >> 4;
      int e0 = et * 64, k00 = kp * 128;
      float* in_s = lds;            // [128][36]
      float* w_s  = lds + 4608;     // [64][36]
      int e_sub = tid & 7, bg = tid >> 3, b0 = bg * 2;
      float accf[8][2];
      #pragma unroll
      for (int je = 0; je < 8; je++) { accf[je][0] = 0.f; accf[je][1] = 0.f; }
      for (int kc = 0; kc < 128; kc += 32) {
        #pragma unroll
        for (int i = 0; i < 2; i++) {
          int flat = tid + 512 * i, r = flat >> 3, f4i = flat & 7;
          float4 v = *(const float4*)(p.Ht + (size_t)r * 2048 + k00 + kc + f4i * 4);
          int sw = (f4i ^ (r >> 2)) & 7;
          *(float4*)&in_s[r * 36 + sw * 4] = v;
        }
        {
          int r = tid >> 3, f4i = tid & 7;
          *(float4*)&w_s[r * 36 + f4i * 4] =
              *(const float4*)(p.fcW + (size_t)(e0 + r) * 2048 + k00 + kc + f4i * 4);
        }
        __syncthreads();
        #pragma unroll
        for (int kq = 0; kq < 8; kq++) {
          int ksw = (kq ^ (bg >> 1)) & 7;
          float4 a0 = *(const float4*)&in_s[b0 * 36 + ksw * 4];
          float4 a1 = *(const float4*)&in_s[(b0 + 1) * 36 + ksw * 4];
          #pragma unroll
          for (int je = 0; je < 8; je++) {
            float4 w4 = *(const float4*)&w_s[(e_sub + 8 * je) * 36 + kq * 4];
            accf[je][0] += a0.x * w4.x + a0.y * w4.y + a0.z * w4.z + a0.w * w4.w;
            accf[je][1] += a1.x * w4.x + a1.y * w4.y + a1.z * w4.z + a1.w * w4.w;
          }
        }
        __syncthreads();
      }
      #pragma unroll
      for (int je = 0; je < 8; je++) {
        int e = e0 + e_sub + 8 * je;
        st_f(&p.fcz[((size_t)kp * 128 + b0) * 1024 + e],     accf[je][0]);
        st_f(&p.fcz[((size_t)kp * 128 + b0 + 1) * 1024 + e], accf[je][1]);
      }
      gbar(p.bar, nbar);
    }

    // ---- final: logits, argmax, softmax, pack next x (blocks 0..127) ----
    if (bid < 128) {
      int b = bid;
      float* sval = lds;
      int*   sidx = (int*)(lds + 512);
      float* ssum = lds + 1024;
      bool end = (__hip_atomic_load(&p.ended[b], __ATOMIC_RELAXED,
                                    __HIP_MEMORY_SCOPE_AGENT) != 0);
      int e2 = tid * 2;
      float vx = p.fcb[e2], vy = p.fcb[e2 + 1];
      #pragma unroll
      for (int q = 0; q < 16; q++) {
        const float* f = &p.fcz[((size_t)q * 128 + b) * 1024 + e2];
        vx += f[0]; vy += f[1];
      }
      if (end) { vx = (e2 == EOSL) ? 1.f : 0.f; vy = (e2 + 1 == EOSL) ? 1.f : 0.f; }
      float bv; int bi;
      if (vy > vx) { bv = vy; bi = e2 + 1; } else { bv = vx; bi = e2; }
      sval[tid] = bv; sidx[tid] = bi;
      __syncthreads();
      for (int s = 256; s > 0; s >>= 1) {
        if (tid < s) {
          float ov = sval[tid + s]; int oi = sidx[tid + s];
          if (ov > sval[tid] || (ov == sval[tid] && oi < sidx[tid])) { sval[tid] = ov; sidx[tid] = oi; }
        }
        __syncthreads();
      }
      float m = sval[0]; int label = sidx[0];
      {
        int k0 = tid * 2;
        float ex = p.emb[(size_t)label * 1024 + k0];
        float ey = p.emb[(size_t)label * 1024 + k0 + 1];
        size_t off = ((size_t)(k0 >> 5) * 8 + (b >> 4)) * 1024
                   + ((b & 15) + 16 * ((k0 >> 3) & 3)) * 8 + (k0 & 7);
        unsigned short h0, l0, h1, l1;
        split_bf(ex, h0, l0); split_bf(ey, h1, l1);
        st_u32((unsigned*)(p.xpx + off),       (unsigned)h0 | ((unsigned)h1 << 16));
        st_u32((unsigned*)(p.xpx + off + 512), (unsigned)l0 | ((unsigned)l1 << 16));
      }
      float ex0 = expf(vx - m), ex1 = expf(vy - m);
      ssum[tid] = ex0 + ex1;
      __syncthreads();
      for (int s = 256; s > 0; s >>= 1) { if (tid < s) ssum[tid] += ssum[tid + s]; __syncthreads(); }
      float inv = 1.f / ssum[0];
      float* orow = p.out + ((size_t)b * NT + t) * NE + e2;
      st_f2(orow, ex0 * inv, ex1 * inv);
      if (tid == 0)
        __hip_atomic_store(&p.ended[b], (end || label == EOSL) ? 1 : 0,
                           __ATOMIC_RELAXED, __HIP_MEMORY_SCOPE_AGENT);
    }
    gbar(p.bar, nbar);
  } // t
}

extern "C" void kernel_launch(void* const* d_in, const int* in_sizes, int n_in,
                              void* d_out, int out_size, void* d_ws, size_t ws_size,
                              hipStream_t stream)
{
  const int*   yy    = (const int*)d_in[0];
  const float* h_t   = (const float*)d_in[1];
  const float* h_tr  = (const float*)d_in[2];
  const float* emb   = (const float*)d_in[4];
  const float* W_ih  = (const float*)d_in[5];
  const float* W_hh  = (const float*)d_in[6];
  const float* b_ih  = (const float*)d_in[7];
  const float* b_hh  = (const float*)d_in[8];
  const float* W_ihr = (const float*)d_in[9];
  const float* W_hhr = (const float*)d_in[10];
  const float* b_ihr = (const float*)d_in[11];
  const float* b_hhr = (const float*)d_in[12];
  const float* c0    = (const float*)d_in[13];
  const float* c0r   = (const float*)d_in[14];
  const float* fc_W  = (const float*)d_in[15];
  const float* fc_b  = (const float*)d_in[16];
  float* out = (float*)d_out;

  float* ws = (float*)d_ws;
  KP p;
  p.c     = ws + C_OFF;
  p.Ht    = ws + HT_OFF;
  p.fcz   = ws + FCZ_OFF;
  p.bias  = ws + BIAS_OFF;
  p.ended = (int*)(ws + END_OFF);
  p.bar   = (int*)(ws + BAR_OFF);
  p.xph   = (unsigned short*)(ws + XPH_OFF);
  p.xpx   = (unsigned short*)(ws + XPX_OFF);
  p.WP    = (const unsigned short*)(ws + WP_OFF);
  p.Wih = W_ih; p.Whh = W_hh; p.Wihr = W_ihr; p.Whhr = W_hhr;
  p.fcW = fc_W; p.fcb = fc_b; p.emb = emb;
  p.out = out;
  bool packed = ws_size >= TOTAL_PACK_F * sizeof(float);

  k_init<<<2048, 256, 0, stream>>>(yy, h_t, h_tr, c0, c0r, b_ih, b_hh, b_ihr, b_hhr,
                                   emb, p.xph, p.xpx, p.c, (float*)p.bias,
                                   p.ended, p.bar);
  if (packed)
    k_packW<<<16384, 256, 0, stream>>>(W_ih, W_hh, W_ihr, W_hhr,
                                       (unsigned short*)p.WP);

  if (packed) k_all<1><<<256, 512, 0, stream>>>(p);
  else        k_all<0><<<256, 512, 0, stream>>>(p);
}

// Round 7
// 47865.784 us; speedup vs baseline: 1.6580x; 1.3945x over previous
//
#include <hip/hip_runtime.h>
#include <math.h>

// B=128, T=256, H=E=1024, L=2, EOS=1
#define NB 128
#define NT 256
#define NH 1024
#define NE 1024
#define G4 4096
#define EOSL 1

// ---------------- workspace layout (float units) ----------------
#define C_OFF    ((size_t)0)          // c [(l*2+dir)][mb 128][b 128][nl 8] = 524,288
#define HT_OFF   ((size_t)524288)     // Ht [2dir][1024n][128b] = 262,144
#define FCZ_OFF  ((size_t)786432)     // fcz [16kp][128b][1024e] = 2,097,152
#define BIAS_OFF ((size_t)2883584)    // 16,384
#define END_OFF  ((size_t)2899968)    // 128
#define BAR_OFF  ((size_t)2900096)    // 512 ints (256 slots + pad)
#define XPH_OFF  ((size_t)2900608)    // 2 parity x 524,288 f
#define XPX_OFF  ((size_t)3949184)    // 131,072 f
#define WP_OFF   ((size_t)4080256)    // 33,554,432 f
#define TOTAL_MIN_F  ((size_t)4080256)
#define TOTAL_PACK_F ((size_t)37634688)   // ~150.5 MB

typedef __attribute__((ext_vector_type(8))) short s8v;   // 8 bf16 for MFMA A/B
typedef __attribute__((ext_vector_type(4))) float f4v;   // MFMA C/D + asm stores
typedef __attribute__((ext_vector_type(2))) float f2v;
typedef __attribute__((ext_vector_type(2))) unsigned u2v;
typedef __attribute__((ext_vector_type(4))) int   i4v;

__device__ __forceinline__ float sigmoid_stable(float x) {
  if (x >= 0.f) return 1.f / (1.f + expf(-x));
  float ex = expf(x);
  return ex / (1.f + ex);
}
__device__ __forceinline__ unsigned short bf_rne(float x) {
  unsigned u = __float_as_uint(x);
  return (unsigned short)((u + 0x7FFFu + ((u >> 16) & 1u)) >> 16);
}
__device__ __forceinline__ void split_bf(float x, unsigned short& h, unsigned short& l) {
  unsigned u = __float_as_uint(x);
  unsigned hb = (u + 0x7FFFu + ((u >> 16) & 1u)) >> 16;
  h = (unsigned short)hb;
  float r = x - __uint_as_float(hb << 16);   // exact
  l = bf_rne(r);
}
__device__ __forceinline__ void cvt8(float4 a0, float4 a1, s8v& hi, s8v& lo)
{
  const float v[8] = {a0.x, a0.y, a0.z, a0.w, a1.x, a1.y, a1.z, a1.w};
  #pragma unroll
  for (int j = 0; j < 8; j++) {
    unsigned short h, l; split_bf(v[j], h, l);
    hi[j] = (short)h; lo[j] = (short)l;
  }
}

// ---- coherent write-through stores/loads (to/from L3 coherence point).
// k_all never creates dirty L2 lines, so buffer_inv never drops data.
// NOTE: asm operands must be scalars or ext_vector types (structs like float4
// are passed indirectly and break the 'v' constraint).
__device__ __forceinline__ void st_f(float* p, float v) {
  asm volatile("global_store_dword %0, %1, off sc0 sc1" :: "v"(p), "v"(v) : "memory");
}
__device__ __forceinline__ void st_u32(unsigned* p, unsigned v) {
  asm volatile("global_store_dword %0, %1, off sc0 sc1" :: "v"(p), "v"(v) : "memory");
}
__device__ __forceinline__ void st_f2(float* p, float a, float b) {
  f2v v; v.x = a; v.y = b;
  asm volatile("global_store_dwordx2 %0, %1, off sc0 sc1" :: "v"(p), "v"(v) : "memory");
}
__device__ __forceinline__ void st_u2(unsigned* p, unsigned a, unsigned b) {
  u2v v; v.x = a; v.y = b;
  asm volatile("global_store_dwordx2 %0, %1, off sc0 sc1" :: "v"(p), "v"(v) : "memory");
}
__device__ __forceinline__ void st_f4(float* p, f4v v) {
  asm volatile("global_store_dwordx4 %0, %1, off sc0 sc1" :: "v"(p), "v"(v) : "memory");
}
__device__ __forceinline__ i4v ld4_coh(const int* p) {
  i4v v;
  asm volatile("global_load_dwordx4 %0, %1, off sc0 sc1\n\ts_waitcnt vmcnt(0)"
               : "=v"(v) : "v"(p) : "memory");
  return v;
}

// ---------------- grid barrier: per-block slot store + 64-lane poll ----------
__device__ __forceinline__ void gbar(int* slots, int target)
{
  asm volatile("s_waitcnt vmcnt(0)" ::: "memory");   // drain this wave's stores
  __syncthreads();                                   // all waves drained
  if (threadIdx.x == 0)
    st_u32((unsigned*)&slots[blockIdx.x], (unsigned)target);
  if (threadIdx.x < 64) {
    const int* sp = slots + threadIdx.x * 4;
    int guard = 0;
    for (;;) {
      i4v v = ld4_coh(sp);
      if (v.x >= target && v.y >= target && v.z >= target && v.w >= target) break;
      __builtin_amdgcn_s_sleep(1);
      if (++guard > (1 << 16)) break;                // degrade, never hang
    }
  }
  __syncthreads();
  asm volatile("buffer_inv sc1" ::: "memory");       // drop stale clean lines
}

// frag layouts (verified rounds 0-5):
//  B (acts): lane l holds B[k=(l>>4)*8+r][b=l&15]; frag = 512 hi + 512 lo shorts
//  A (wgts): lane l holds A[slot=l&15][k=(l>>4)*8+r]
//  gate-interleaved mtiles: mtile=mb*2+half; slot s -> m = gate*1024+mb*8+(s&7),
//  gate = half*2+(s>>3).  C/D: col=lane&15 (b), row slot=(lane>>4)*4+reg.

// ---------------- init ----------------
__global__ void k_init(const int* yy, const float* h_t, const float* h_tr,
                       const float* c0, const float* c0r,
                       const float* b_ih, const float* b_hh,
                       const float* b_ihr, const float* b_hhr,
                       const float* emb,
                       unsigned short* xph, unsigned short* xpx,
                       float* call, float* bias, int* ended, int* bar)
{
  int idx = blockIdx.x * 256 + threadIdx.x;   // 2048 blocks -> 524288
  if (idx < 2 * 2048 * 128) {                 // XPH parity-0
    int dir = idx / (2048 * 128); int rem = idx % (2048 * 128);
    int row = rem >> 7, b = rem & 127;
    int l = row >> 10, n = row & 1023;
    const float* src = dir ? h_tr : h_t;
    float v = src[((size_t)l * 128 + b) * 1024 + n];
    unsigned short h, lo; split_bf(v, h, lo);
    size_t off = ((size_t)(dir * 64 + (row >> 5)) * 8 + (b >> 4)) * 1024
               + ((b & 15) + 16 * ((n >> 3) & 3)) * 8 + (n & 7);
    xph[off] = h; xph[off + 512] = lo;
  }
  if (idx < 4 * 1024 * 128) {                 // c [(ld)][mb][b][nl]
    int ld = idx / (1024 * 128); int l = ld >> 1;
    int rem = idx % (1024 * 128);
    int mb = rem >> 10, nl = rem & 7;
    const float* cs = (ld & 1) ? c0r : c0;
    call[idx] = cs[l * 1024 + mb * 8 + nl];
  }
  if (idx < 4 * 4096) {                       // bias[(l*2+dir)][m]
    int ld = idx / 4096; int l = ld >> 1, dir = ld & 1;
    int m = idx & 4095;
    bias[idx] = (dir ? b_ihr : b_ih)[l * 4096 + m] + (dir ? b_hhr : b_hh)[l * 4096 + m];
  }
  if (idx < 128 * 1024) {                     // XPX: x0 = emb[yy[:,0]]
    int b = idx >> 10, k = idx & 1023;
    int e = yy[b * NT];
    float v = emb[(size_t)e * 1024 + k];
    unsigned short h, lo; split_bf(v, h, lo);
    size_t off = ((size_t)(k >> 5) * 8 + (b >> 4)) * 1024
               + ((b & 15) + 16 * ((k >> 3) & 3)) * 8 + (k & 7);
    xpx[off] = h; xpx[off + 512] = lo;
  }
  if (idx < NB) ended[idx] = 0;
  if (idx < 512) bar[idx] = 0;
}

// ---------------- one-time weight pre-split (gate-interleaved mtiles) --------
__global__ void k_packW(const float* W_ih, const float* W_hh,
                        const float* W_ihr, const float* W_hhr,
                        unsigned short* WP)
{
  int idx = blockIdx.x * 256 + threadIdx.x;   // 16384 blocks -> 4,194,304
  int l = idx & 63;
  int frag = idx >> 6;
  int ktile = frag & 63;
  int mtile = (frag >> 6) & 255;
  int ld = frag >> 14;
  int layer = ld >> 1, dir = ld & 1;
  int s = l & 15;
  int mbb = mtile >> 1, half = mtile & 1;
  int gate = half * 2 + (s >> 3);
  int m = gate * 1024 + mbb * 8 + (s & 7);
  int kg = ktile * 32 + (l >> 4) * 8;
  const float* base;
  if (kg < 1024) base = (dir ? W_ihr : W_ih) + ((size_t)layer * 4096 + m) * 1024 + kg;
  else           base = (dir ? W_hhr : W_hh) + ((size_t)layer * 4096 + m) * 1024 + (kg - 1024);
  float4 a0 = *(const float4*)base, a1 = *(const float4*)(base + 4);
  s8v hi, lo; cvt8(a0, a1, hi, lo);
  unsigned short* outp = WP + (size_t)frag * 1024 + l * 8;
  *(s8v*)outp = hi;
  *(s8v*)(outp + 512) = lo;
}

// ---------------- reduction-tree helpers (verified round 3) ------------------
__device__ __forceinline__ void red_write(float* red, int slot, int l, const f4v (&acc)[2][8])
{
  #pragma unroll
  for (int mt = 0; mt < 2; mt++)
    #pragma unroll
    for (int bt = 0; bt < 8; bt++)
      *(f4v*)&red[(size_t)slot * 4096 + (mt * 8 + bt) * 256 + l * 4] = acc[mt][bt];
}
__device__ __forceinline__ void red_add(const float* red, int slot, int l, f4v (&acc)[2][8])
{
  #pragma unroll
  for (int mt = 0; mt < 2; mt++)
    #pragma unroll
    for (int bt = 0; bt < 8; bt++)
      acc[mt][bt] += *(const f4v*)&red[(size_t)slot * 4096 + (mt * 8 + bt) * 256 + l * 4];
}

struct KP {
  const unsigned short* WP;
  const float* Wih; const float* Whh; const float* Wihr; const float* Whhr;
  const float* bias; float* c; float* Ht; float* fcz;
  unsigned short* xph; unsigned short* xpx;
  const float* fcW; const float* fcb; const float* emb;
  float* out; int* ended; int* bar;
};

// ---------------- persistent kernel: all 256 steps, 4 grid barriers/step -----
template<int PACKED>
__global__ __launch_bounds__(512, 2) void k_all(KP p)
{
  __shared__ __align__(16) float lds[16384];           // 64 KB, reused per phase
  const int bid = blockIdx.x, tid = threadIdx.x;
  const int l = tid & 63, w = tid >> 6;                // w = K-chunk 0..7 (gemm)
  const int dir = bid >> 7, mb = bid & 127;
  const int lr = l & 15, lk = l >> 4;
  int nbar = 0;

  for (int t = 0; t < NT; t++) {
    unsigned short* xpR = p.xph + (size_t)(t & 1) * 1048576;        // read h
    unsigned short* xpW = p.xph + (size_t)((t & 1) ^ 1) * 1048576;  // write h

    for (int layer = 0; layer < 2; layer++) {
      // ---- per-wave B fragment base ----
      const unsigned short* Bb;
      if (layer == 0)
        Bb = (w < 4) ? p.xpx + (size_t)w * 65536
                     : xpR + (size_t)(dir * 64 + (w - 4) * 8) * 8192;
      else
        Bb = (w < 4) ? xpW + (size_t)(dir * 64 + w * 8) * 8192
                     : xpR + (size_t)(dir * 64 + 32 + (w - 4) * 8) * 8192;
      Bb += l * 8;

      f4v acc[2][8];
      #pragma unroll
      for (int mt = 0; mt < 2; mt++)
        #pragma unroll
        for (int bt = 0; bt < 8; bt++)
          acc[mt][bt] = (f4v)(0.0f);

      if (PACKED) {
        const unsigned short* Wb = p.WP + (size_t)(layer * 2 + dir) * 16777216ULL
            + (((size_t)(mb * 2) * 64 + (size_t)w * 8) << 10) + l * 8;
        s8v whc[2], wlc[2];
        #pragma unroll
        for (int mt = 0; mt < 2; mt++) {
          const unsigned short* q = Wb + ((size_t)(mt * 64) << 10);
          whc[mt] = *(const s8v*)q; wlc[mt] = *(const s8v*)(q + 512);
        }
        #pragma unroll 1
        for (int kk = 0; kk < 8; kk++) {
          s8v bh[8], bl[8];
          #pragma unroll
          for (int bt = 0; bt < 8; bt++) {
            const unsigned short* q = Bb + ((size_t)(kk * 8 + bt) << 10);
            bh[bt] = *(const s8v*)q; bl[bt] = *(const s8v*)(q + 512);
          }
          s8v whn[2], wln[2];
          if (kk < 7) {
            #pragma unroll
            for (int mt = 0; mt < 2; mt++) {
              const unsigned short* q = Wb + ((size_t)(mt * 64 + kk + 1) << 10);
              whn[mt] = *(const s8v*)q; wln[mt] = *(const s8v*)(q + 512);
            }
          }
          #pragma unroll
          for (int mt = 0; mt < 2; mt++)
            #pragma unroll
            for (int bt = 0; bt < 8; bt++) {
              acc[mt][bt] = __builtin_amdgcn_mfma_f32_16x16x32_bf16(whc[mt], bh[bt], acc[mt][bt], 0, 0, 0);
              acc[mt][bt] = __builtin_amdgcn_mfma_f32_16x16x32_bf16(whc[mt], bl[bt], acc[mt][bt], 0, 0, 0);
              acc[mt][bt] = __builtin_amdgcn_mfma_f32_16x16x32_bf16(wlc[mt], bh[bt], acc[mt][bt], 0, 0, 0);
            }
          if (kk < 7) {
            whc[0] = whn[0]; whc[1] = whn[1];
            wlc[0] = wln[0]; wlc[1] = wln[1];
          }
        }
      } else {
        const float* Wsel = ((w < 4) ? (dir ? p.Wihr : p.Wih) : (dir ? p.Whhr : p.Whh))
                          + (size_t)layer * 4194304;
        int col0 = (w & 3) * 256 + lk * 8;
        const float* Wrow[2];
        Wrow[0] = Wsel + ((size_t)(((lr >> 3)) * 1024 + mb * 8 + (lr & 7))) * 1024 + col0;
        Wrow[1] = Wsel + ((size_t)((2 + (lr >> 3)) * 1024 + mb * 8 + (lr & 7))) * 1024 + col0;
        float4 ac[2][2];
        #pragma unroll
        for (int mt = 0; mt < 2; mt++) {
          ac[mt][0] = *(const float4*)(Wrow[mt]);
          ac[mt][1] = *(const float4*)(Wrow[mt] + 4);
        }
        #pragma unroll 1
        for (int kk = 0; kk < 8; kk++) {
          s8v bh[8], bl[8];
          #pragma unroll
          for (int bt = 0; bt < 8; bt++) {
            const unsigned short* q = Bb + ((size_t)(kk * 8 + bt) << 10);
            bh[bt] = *(const s8v*)q; bl[bt] = *(const s8v*)(q + 512);
          }
          float4 an[2][2];
          if (kk < 7) {
            #pragma unroll
            for (int mt = 0; mt < 2; mt++) {
              an[mt][0] = *(const float4*)(Wrow[mt] + (kk + 1) * 32);
              an[mt][1] = *(const float4*)(Wrow[mt] + (kk + 1) * 32 + 4);
            }
          }
          #pragma unroll
          for (int mt = 0; mt < 2; mt++) {
            s8v wh, wl;
            cvt8(ac[mt][0], ac[mt][1], wh, wl);
            #pragma unroll
            for (int bt = 0; bt < 8; bt++) {
              acc[mt][bt] = __builtin_amdgcn_mfma_f32_16x16x32_bf16(wh, bh[bt], acc[mt][bt], 0, 0, 0);
              acc[mt][bt] = __builtin_amdgcn_mfma_f32_16x16x32_bf16(wh, bl[bt], acc[mt][bt], 0, 0, 0);
              acc[mt][bt] = __builtin_amdgcn_mfma_f32_16x16x32_bf16(wl, bh[bt], acc[mt][bt], 0, 0, 0);
            }
          }
          if (kk < 7) {
            #pragma unroll
            for (int mt = 0; mt < 2; mt++) { ac[mt][0] = an[mt][0]; ac[mt][1] = an[mt][1]; }
          }
        }
      }

      // ---- in-block K reduction: 8 -> 4 -> 2 -> zs stage ----
      if (w >= 4) red_write(lds, w - 4, l, acc);
      __syncthreads();
      if (w < 4) red_add(lds, w, l, acc);
      __syncthreads();
      if (w == 2 || w == 3) red_write(lds, w - 2, l, acc);
      __syncthreads();
      if (w < 2) red_add(lds, w, l, acc);
      __syncthreads();
      if (w < 2) red_write(lds, w, l, acc);
      __syncthreads();
      float* zs = lds + 8192;                 // [2mt][16slot][128b]
      #pragma unroll
      for (int vi = 0; vi < 2; vi++) {
        int v = tid + vi * 512;
        f4v s = *(const f4v*)&lds[(size_t)v * 4];
        s += *(const f4v*)&lds[4096 + (size_t)v * 4];
        int frag = v >> 6, lane = v & 63;
        int mt = frag >> 3, bt = frag & 7;
        int s0 = (lane >> 4) * 4, bcol = bt * 16 + (lane & 15);
        #pragma unroll
        for (int r = 0; r < 4; r++)
          zs[mt * 2048 + (s0 + r) * 128 + bcol] = s[r];
      }
      __syncthreads();

      // ---- fused gates: thread = (b, 4 consecutive n); coalesced stores ----
      int ldg = layer * 2 + dir;
      if (tid < 256) {
        int b = tid & 127, q = tid >> 7;
        float* cp = p.c + ((((size_t)ldg * 128 + mb) * 128 + b) * 8 + q * 4);
        f4v cold = *(const f4v*)cp;
        f4v cnew;
        float hs[4];
        #pragma unroll
        for (int j = 0; j < 4; j++) {
          int nl = q * 4 + j;
          int n = mb * 8 + nl;
          float iv = zs[nl * 128 + b]              + p.bias[ldg * 4096 + n];
          float fv = zs[(nl + 8) * 128 + b]        + p.bias[ldg * 4096 + 1024 + n];
          float gv = zs[2048 + nl * 128 + b]       + p.bias[ldg * 4096 + 2048 + n];
          float ov = zs[2048 + (nl + 8) * 128 + b] + p.bias[ldg * 4096 + 3072 + n];
          float co = cold[j];
          float cn = sigmoid_stable(fv) * co + sigmoid_stable(iv) * tanhf(gv);
          float hn = sigmoid_stable(ov) * tanhf(cn);
          cnew[j] = cn;
          hs[j] = hn;
        }
        st_f4(cp, cnew);
        unsigned short hh[4], ll[4];
        #pragma unroll
        for (int j = 0; j < 4; j++) split_bf(hs[j], hh[j], ll[j]);
        int kt = layer * 32 + (mb >> 2);
        size_t off = ((size_t)(dir * 64 + kt) * 8 + (b >> 4)) * 1024
                   + ((size_t)((b & 15) + 16 * (mb & 3))) * 8 + q * 4;
        st_u2((unsigned*)(xpW + off),
              (unsigned)hh[0] | ((unsigned)hh[1] << 16),
              (unsigned)hh[2] | ((unsigned)hh[3] << 16));
        st_u2((unsigned*)(xpW + off + 512),
              (unsigned)ll[0] | ((unsigned)ll[1] << 16),
              (unsigned)ll[2] | ((unsigned)ll[3] << 16));
        if (layer == 1) {
          #pragma unroll
          for (int j = 0; j < 4; j++) {
            int n = mb * 8 + q * 4 + j;
            st_f(p.Ht + (size_t)dir * 131072 + (size_t)n * 128 + b, hs[j]);
          }
        }
      }
      ++nbar; gbar(p.bar, nbar);
    } // layer

    // ---- fc: fcz[kp][b][e] partials, 256 blocks = (16 et, 16 kp) ----
    {
      int et = bid & 15, kp = bid >> 4;
      int e0 = et * 64, k00 = kp * 128;
      float* in_s = lds;            // [128][36]
      float* w_s  = lds + 4608;     // [64][36]
      int e_sub = tid & 7, bg = tid >> 3, b0 = bg * 2;
      float accf[8][2];
      #pragma unroll
      for (int je = 0; je < 8; je++) { accf[je][0] = 0.f; accf[je][1] = 0.f; }
      for (int kc = 0; kc < 128; kc += 32) {
        #pragma unroll
        for (int i = 0; i < 2; i++) {
          int flat = tid + 512 * i, r = flat >> 3, f4i = flat & 7;
          float4 v = *(const float4*)(p.Ht + (size_t)r * 2048 + k00 + kc + f4i * 4);
          int sw = (f4i ^ (r >> 2)) & 7;
          *(float4*)&in_s[r * 36 + sw * 4] = v;
        }
        {
          int r = tid >> 3, f4i = tid & 7;
          *(float4*)&w_s[r * 36 + f4i * 4] =
              *(const float4*)(p.fcW + (size_t)(e0 + r) * 2048 + k00 + kc + f4i * 4);
        }
        __syncthreads();
        #pragma unroll
        for (int kq = 0; kq < 8; kq++) {
          int ksw = (kq ^ (bg >> 1)) & 7;
          float4 a0 = *(const float4*)&in_s[b0 * 36 + ksw * 4];
          float4 a1 = *(const float4*)&in_s[(b0 + 1) * 36 + ksw * 4];
          #pragma unroll
          for (int je = 0; je < 8; je++) {
            float4 w4 = *(const float4*)&w_s[(e_sub + 8 * je) * 36 + kq * 4];
            accf[je][0] += a0.x * w4.x + a0.y * w4.y + a0.z * w4.z + a0.w * w4.w;
            accf[je][1] += a1.x * w4.x + a1.y * w4.y + a1.z * w4.z + a1.w * w4.w;
          }
        }
        __syncthreads();
      }
      // stage to LDS transpose, then 64B-contiguous coherent stores
      #pragma unroll
      for (int je = 0; je < 8; je++) {
        lds[(b0    ) * 68 + e_sub + 8 * je] = accf[je][0];
        lds[(b0 + 1) * 68 + e_sub + 8 * je] = accf[je][1];
      }
      __syncthreads();
      {
        int row = tid >> 2, ch = tid & 3;
        float* gp = p.fcz + ((size_t)kp * 128 + row) * 1024 + e0 + ch * 16;
        #pragma unroll
        for (int i = 0; i < 4; i++)
          st_f4(gp + 4 * i, *(const f4v*)&lds[row * 68 + ch * 16 + 4 * i]);
      }
      ++nbar; gbar(p.bar, nbar);
    }

    // ---- final: logits, argmax, softmax, pack next x (blocks 0..127) ----
    if (bid < 128) {
      int b = bid;
      float* sval = lds;
      int*   sidx = (int*)(lds + 512);
      float* ssum = lds + 1024;
      bool end = (p.ended[b] != 0);
      int e2 = tid * 2;
      float vx = p.fcb[e2], vy = p.fcb[e2 + 1];
      #pragma unroll
      for (int q = 0; q < 16; q++) {
        const float* f = &p.fcz[((size_t)q * 128 + b) * 1024 + e2];
        vx += f[0]; vy += f[1];
      }
      if (end) { vx = (e2 == EOSL) ? 1.f : 0.f; vy = (e2 + 1 == EOSL) ? 1.f : 0.f; }
      float bv; int bi;
      if (vy > vx) { bv = vy; bi = e2 + 1; } else { bv = vx; bi = e2; }
      sval[tid] = bv; sidx[tid] = bi;
      __syncthreads();
      for (int s = 256; s > 0; s >>= 1) {
        if (tid < s) {
          float ov = sval[tid + s]; int oi = sidx[tid + s];
          if (ov > sval[tid] || (ov == sval[tid] && oi < sidx[tid])) { sval[tid] = ov; sidx[tid] = oi; }
        }
        __syncthreads();
      }
      float m = sval[0]; int label = sidx[0];
      {
        int k0 = tid * 2;
        float ex = p.emb[(size_t)label * 1024 + k0];
        float ey = p.emb[(size_t)label * 1024 + k0 + 1];
        size_t off = ((size_t)(k0 >> 5) * 8 + (b >> 4)) * 1024
                   + ((b & 15) + 16 * ((k0 >> 3) & 3)) * 8 + (k0 & 7);
        unsigned short h0, l0, h1, l1;
        split_bf(ex, h0, l0); split_bf(ey, h1, l1);
        st_u32((unsigned*)(p.xpx + off),       (unsigned)h0 | ((unsigned)h1 << 16));
        st_u32((unsigned*)(p.xpx + off + 512), (unsigned)l0 | ((unsigned)l1 << 16));
      }
      float ex0 = expf(vx - m), ex1 = expf(vy - m);
      ssum[tid] = ex0 + ex1;
      __syncthreads();
      for (int s = 256; s > 0; s >>= 1) { if (tid < s) ssum[tid] += ssum[tid + s]; __syncthreads(); }
      float inv = 1.f / ssum[0];
      float* orow = p.out + ((size_t)b * NT + t) * NE + e2;
      st_f2(orow, ex0 * inv, ex1 * inv);
      if (tid == 0)
        st_u32((unsigned*)&p.ended[b], (end || label == EOSL) ? 1u : 0u);
    }
    ++nbar; gbar(p.bar, nbar);
  } // t
}

extern "C" void kernel_launch(void* const* d_in, const int* in_sizes, int n_in,
                              void* d_out, int out_size, void* d_ws, size_t ws_size,
                              hipStream_t stream)
{
  const int*   yy    = (const int*)d_in[0];
  const float* h_t   = (const float*)d_in[1];
  const float* h_tr  = (const float*)d_in[2];
  const float* emb   = (const float*)d_in[4];
  const float* W_ih  = (const float*)d_in[5];
  const float* W_hh  = (const float*)d_in[6];
  const float* b_ih  = (const float*)d_in[7];
  const float* b_hh  = (const float*)d_in[8];
  const float* W_ihr = (const float*)d_in[9];
  const float* W_hhr = (const float*)d_in[10];
  const float* b_ihr = (const float*)d_in[11];
  const float* b_hhr = (const float*)d_in[12];
  const float* c0    = (const float*)d_in[13];
  const float* c0r   = (const float*)d_in[14];
  const float* fc_W  = (const float*)d_in[15];
  const float* fc_b  = (const float*)d_in[16];
  float* out = (float*)d_out;

  float* ws = (float*)d_ws;
  KP p;
  p.c     = ws + C_OFF;
  p.Ht    = ws + HT_OFF;
  p.fcz   = ws + FCZ_OFF;
  p.bias  = ws + BIAS_OFF;
  p.ended = (int*)(ws + END_OFF);
  p.bar   = (int*)(ws + BAR_OFF);
  p.xph   = (unsigned short*)(ws + XPH_OFF);
  p.xpx   = (unsigned short*)(ws + XPX_OFF);
  p.WP    = (const unsigned short*)(ws + WP_OFF);
  p.Wih = W_ih; p.Whh = W_hh; p.Wihr = W_ihr; p.Whhr = W_hhr;
  p.fcW = fc_W; p.fcb = fc_b; p.emb = emb;
  p.out = out;
  bool packed = ws_size >= TOTAL_PACK_F * sizeof(float);

  k_init<<<2048, 256, 0, stream>>>(yy, h_t, h_tr, c0, c0r, b_ih, b_hh, b_ihr, b_hhr,
                                   emb, p.xph, p.xpx, p.c, (float*)p.bias,
                                   p.ended, p.bar);
  if (packed)
    k_packW<<<16384, 256, 0, stream>>>(W_ih, W_hh, W_ihr, W_hhr,
                                       (unsigned short*)p.WP);

  if (packed) k_all<1><<<256, 512, 0, stream>>>(p);
  else        k_all<0><<<256, 512, 0, stream>>>(p);
}